// Round 7
// baseline (137.682 us; speedup 1.0000x reference)
//
#include <hip/hip_runtime.h>

// SINDy: out[65536,32] = Theta(z)[65536,6545] @ (Xi*Xi_mask)[6545,32]
// Round-7: split-K x4 (1 tile x 4 k-ranges per 256-thr block, grid 2048 =
// 8 blocks/CU -> 8 waves/SIMD), LDS diet (column-major z table 4.2KB +
// 2-buffer combine 8.2KB), scalar meta from rodata staged 2 iters ahead in
// SGPRs, offsets pre-scaled x128, pair-granularity B register dbuf,
// coalesced prep (block per 4 granules, (jj,n) mapping + LDS repack).
// MFMA 32x32x16_bf16 layouts (verified rounds 1-6):
//   A[m][k]: m=lane&31, k=(lane>>5)*8+jj
//   B[k][n]: n=lane&31, k=(lane>>5)*8+jj
//   C/D:     col=lane&31, row=(reg&3)+8*(reg>>2)+4*(lane>>5)

#define Z 32
#define ROWS 65536
#define NBLK (ROWS / 32)         // 2048 blocks, one 32x32 tile each, 4 k-splits

#define NCHUNK 552               // 36 + 84 + 160 + 272 (quarter-segments)
#define NGRAN (NCHUNK * 2)

typedef short short8 __attribute__((ext_vector_type(8)));
typedef float f32x16 __attribute__((ext_vector_type(16)));
typedef float float2v __attribute__((ext_vector_type(2)));

struct Sched {
    int nq[4];                 // chunks per quarter-segment
    unsigned mlo[NCHUNK];      // granule0: (i*128) | (j*128)<<16 (col-major byte offs)
    unsigned mhi[NCHUNK];      // granule1: same
    short rt[NGRAN * 8];       // library row per (granule, jj), -1 = pad
};

constexpr Sched make_sched() {
    Sched s{};
    short gi[NGRAN] = {}, gj[NGRAN] = {};
    char gt[NGRAN] = {}, gq[NGRAN] = {};
    int tidx[32][32] = {}, pidx[32] = {};
    {
        int n = 0;
        for (int a = 0; a < 32; ++a)
            for (int b = a; b < 32; ++b) { tidx[a][b] = n; n += 32 - b; }
        for (int i = 0; i < 32; ++i) pidx[i] = i * 32 - i * (i - 1) / 2;
    }
    int g = 0;
    for (int q = 0; q < 4; ++q) {
        int g0 = g;
        // triples (a<=b): granule covers k in [8q,8q+8) for k>=b -> need b>>3 <= q
        for (int b = 0; b < 32; ++b)
            if ((b >> 3) <= q)
                for (int a = 0; a <= b; ++a) { gi[g]=(short)a; gj[g]=(short)b; gt[g]=0; gq[g]=(char)q; ++g; }
        // pairs (b,32): theta = z_b*z_k, valid k<=b -> need b>>3 >= q
        for (int b = 0; b < 32; ++b)
            if ((b >> 3) >= q) { gi[g]=(short)b; gj[g]=32; gt[g]=1; gq[g]=(char)q; ++g; }
        // linear: theta = z_k
        gi[g]=32; gj[g]=32; gt[g]=2; gq[g]=(char)q; ++g;
        // pad quarter to a multiple of 8 granules (4 chunks)
        while ((g - g0) & 7) { gi[g]=32; gj[g]=32; gt[g]=3; gq[g]=(char)q; ++g; }
        s.nq[q] = (g - g0) / 2;
    }
    for (int c = 0; c < NCHUNK; ++c) {
        s.mlo[c] = ((unsigned)gi[2*c]   * 128u) | (((unsigned)gj[2*c]   * 128u) << 16);
        s.mhi[c] = ((unsigned)gi[2*c+1] * 128u) | (((unsigned)gj[2*c+1] * 128u) << 16);
    }
    for (int gg = 0; gg < NGRAN; ++gg) {
        int i = gi[gg], j = gj[gg], ty = gt[gg], q = gq[gg];
        for (int jj = 0; jj < 8; ++jj) {
            int k = 8 * q + jj, row = -1;
            if (ty == 0)      { if (k >= j) row = 561 + tidx[i][j] + (k - j); }   // triple (i,j,k)
            else if (ty == 1) { if (k <= i) row = 33 + pidx[k] + (i - k); }       // pair (k,i)
            else if (ty == 2) { row = 1 + k; }                                    // linear z_k
            s.rt[gg * 8 + jj] = (short)row;
        }
    }
    return s;
}
constexpr Sched S = make_sched();
static_assert(S.nq[0] == 36 && S.nq[1] == 84 && S.nq[2] == 160 && S.nq[3] == 272, "chunk counts");

__device__ __forceinline__ unsigned pack_bf16(float s0, float s1) {
#if __has_builtin(__builtin_amdgcn_cvt_pk_bf16_f32)
    return __builtin_bit_cast(unsigned, __builtin_amdgcn_cvt_pk_bf16_f32(s0, s1));
#else
    unsigned b0 = __builtin_bit_cast(unsigned, s0) + 0x8000u;
    unsigned b1 = __builtin_bit_cast(unsigned, s1) + 0x8000u;
    return __builtin_amdgcn_perm(b1, b0, 0x07060302u);   // lo16=s0, hi16=s1
#endif
}

// ---- prep: coalesced. One block per 4 granules; per granule the 256
// threads map (jj = tid>>5, n = tid&31) -> Xi reads are 128B-contiguous
// per jj-group; repack to B-fragment uint2s via LDS.
__global__ void sindy_prep(const float* __restrict__ Xi,
                           const float* __restrict__ Xi_mask,
                           uint2* __restrict__ Bp2, size_t ws_size) {
    __shared__ unsigned short sh[8][32];
    const int tid = threadIdx.x;
    const int jj = tid >> 5, n = tid & 31;
#pragma unroll
    for (int pass = 0; pass < 4; ++pass) {
        int g = blockIdx.x * 4 + pass;
        int row = S.rt[g * 8 + jj];
        float f = 0.0f;
        if (row >= 0) f = Xi[row * Z + n] * Xi_mask[row * Z + n];
        unsigned u = __builtin_bit_cast(unsigned, f);
        sh[jj][n] = (unsigned short)((u + 0x7FFFu + ((u >> 16) & 1u)) >> 16);  // RNE
        __syncthreads();
        if (tid < 64) {
            int n2 = tid & 31, rep = tid >> 5;
            unsigned v0 = sh[4*rep+0][n2], v1 = sh[4*rep+1][n2];
            unsigned v2 = sh[4*rep+2][n2], v3 = sh[4*rep+3][n2];
            int c = g >> 1, h = g & 1;
            size_t idx = ((size_t)c * 64 + h * 32 + n2) * 2 + rep;
            if ((idx + 1) * 8 <= ws_size)
                Bp2[idx] = uint2{v0 | (v1 << 16), v2 | (v3 << 16)};
        }
        __syncthreads();
    }
}

// ---- k-range runner: pair-granularity loop, B dbuf 1 pair ahead,
// z-loads 1 pair ahead, scalar meta staged 2 pairs ahead ----
template<int Q, bool LAST>
__device__ __forceinline__ void seg(int c0, int cend,
                                    const uint4* __restrict__ bpl,  // Bp + lane
                                    const char* __restrict__ zb,    // lds zs + 4*m
                                    bool hi, f32x16& acc) {
    // this quarter's z values (static offsets, conflict-free)
    float2v zqA, zqB, zqC, zqD;
    zqA.x = *(const float*)(zb + (8*Q+0)*128); zqA.y = *(const float*)(zb + (8*Q+1)*128);
    zqB.x = *(const float*)(zb + (8*Q+2)*128); zqB.y = *(const float*)(zb + (8*Q+3)*128);
    zqC.x = *(const float*)(zb + (8*Q+4)*128); zqC.y = *(const float*)(zb + (8*Q+5)*128);
    zqD.x = *(const float*)(zb + (8*Q+6)*128); zqD.y = *(const float*)(zb + (8*Q+7)*128);

    auto chunk = [&](float pp, const uint4& bv) {
        float2v p2; p2.x = pp; p2.y = pp;
        union { unsigned u[4]; short8 sv; } a;
        float2v t0 = p2 * zqA; a.u[0] = pack_bf16(t0.x, t0.y);
        float2v t1 = p2 * zqB; a.u[1] = pack_bf16(t1.x, t1.y);
        float2v t2 = p2 * zqC; a.u[2] = pack_bf16(t2.x, t2.y);
        float2v t3 = p2 * zqD; a.u[3] = pack_bf16(t3.x, t3.y);
        union { uint4 v; short8 sv; } b; b.v = bv;
        acc = __builtin_amdgcn_mfma_f32_32x32x16_bf16(a.sv, b.sv, acc, 0, 0, 0);
    };

    const uint4* p = bpl + (size_t)c0 * 64;
    uint4 cur0 = p[0], cur1 = p[64];

    // prologue: products for pair0 (cold), meta for pair1 staged (selected)
    unsigned mw0 = hi ? S.mhi[c0]     : S.mlo[c0];
    unsigned mw1 = hi ? S.mhi[c0 + 1] : S.mlo[c0 + 1];
    float pC0 = (*(const float*)(zb + (mw0 & 0xFFFFu))) * (*(const float*)(zb + (mw0 >> 16)));
    float pC1 = (*(const float*)(zb + (mw1 & 0xFFFFu))) * (*(const float*)(zb + (mw1 >> 16)));
    int c1 = (c0 + 2 < cend) ? c0 + 2 : c0;
    unsigned mA0 = hi ? S.mhi[c1] : S.mlo[c1];
    unsigned mA1 = hi ? S.mhi[c1 + 1] : S.mlo[c1 + 1];

    for (int c = c0; c < cend; c += 2) {
        bool more = (c + 2 < cend);
        // z loads for pair c+2 from staged meta
        float zi0 = *(const float*)(zb + (mA0 & 0xFFFFu));
        float zj0 = *(const float*)(zb + (mA0 >> 16));
        float zi1 = *(const float*)(zb + (mA1 & 0xFFFFu));
        float zj1 = *(const float*)(zb + (mA1 >> 16));
        // meta for pair c+4 (scalar loads; clamped uniform index)
        int cn = (c + 4 < cend) ? c + 4 : c;
        unsigned mB0 = hi ? S.mhi[cn] : S.mlo[cn];
        unsigned mB1 = hi ? S.mhi[cn + 1] : S.mlo[cn + 1];
        // B prefetch (continues into the next piece's stream unless LAST end)
        int offn = (more || !LAST) ? 128 : 0;
        uint4 n0 = p[offn], n1 = p[offn + 64];
        // MFMA pair c
        chunk(pC0, cur0);
        chunk(pC1, cur1);
        // retire stages
        pC0 = zi0 * zj0; pC1 = zi1 * zj1;
        mA0 = mB0; mA1 = mB1;
        cur0 = n0; cur1 = n1;
        p += offn;
    }
}

// ---- main: 256 thr = 4 waves = 1 tile x 4 k-splits [0,136,276,416,552) ----
__global__ __launch_bounds__(256, 8) void sindy_mfma(const float* __restrict__ z,
                                                     const float* __restrict__ Xi,
                                                     const float* __restrict__ Xi_mask,
                                                     const uint4* __restrict__ Bp,
                                                     float* __restrict__ out) {
    const int lane = threadIdx.x & 63;
    const int kh = threadIdx.x >> 6;     // k-split 0..3
    const int m = lane & 31;
    const int half = lane >> 5;
    const long R = (long)blockIdx.x * 32;

    __shared__ float zs[33][32];   // column-major: zs[k][m]; bank = m, conflict-free
    __shared__ float cs[2][32][32];

    // stage z column-major: wave kh writes k in [8kh, 8kh+8)
    {
        const float4* z4 = (const float4*)(z + (R + m) * Z + 8 * kh);
        float4 v0 = z4[0], v1 = z4[1];
        zs[8*kh+0][m] = v0.x; zs[8*kh+1][m] = v0.y; zs[8*kh+2][m] = v0.z; zs[8*kh+3][m] = v0.w;
        zs[8*kh+4][m] = v1.x; zs[8*kh+5][m] = v1.y; zs[8*kh+6][m] = v1.z; zs[8*kh+7][m] = v1.w;
        if (kh == 0 && half == 0) zs[32][m] = 1.0f;   // z~[32] = 1.0 sentinel
    }
    __syncthreads();

    f32x16 acc = {};
    const char* zb = (const char*)&zs[0][0] + 4 * m;
    const uint4* bpl = Bp + lane;
    const bool hi = (half != 0);

    // k-ranges (piece boundaries at quarter edges 36/120/280)
    if (kh == 0) {
        seg<0, false>(  0,  36, bpl, zb, hi, acc);
        seg<1, false>( 36, 120, bpl, zb, hi, acc);
        seg<2, true >(120, 136, bpl, zb, hi, acc);
    } else if (kh == 1) {
        seg<2, true >(136, 276, bpl, zb, hi, acc);
    } else if (kh == 2) {
        seg<2, false>(276, 280, bpl, zb, hi, acc);
        seg<3, true >(280, 416, bpl, zb, hi, acc);
    } else {
        seg<3, true >(416, 552, bpl, zb, hi, acc);
    }

    // combine: kh1 -> cs0, kh3 -> cs1
    if (kh == 1 || kh == 3) {
        float (*dst)[32] = cs[kh >> 1];
#pragma unroll
        for (int r = 0; r < 16; ++r) {
            int row = (r & 3) + 8 * (r >> 2) + 4 * half;
            dst[row][m] = acc[r];
        }
    }
    __syncthreads();
    if (kh == 0) {
#pragma unroll
        for (int r = 0; r < 16; ++r) {
            int row = (r & 3) + 8 * (r >> 2) + 4 * half;
            acc[r] += cs[0][row][m];
        }
    } else if (kh == 2) {
#pragma unroll
        for (int r = 0; r < 16; ++r) {
            int row = (r & 3) + 8 * (r >> 2) + 4 * half;
            cs[1][row][m] += acc[r];   // in-place: same lane reads+writes same addr
        }
    }
    __syncthreads();
    if (kh == 0) {
        const float bias = Xi[m] * Xi_mask[m];   // library row 0 (ones), col n = m
        float* orow = out + R * Z;
#pragma unroll
        for (int r = 0; r < 16; ++r) {
            int row = (r & 3) + 8 * (r >> 2) + 4 * half;
            orow[row * Z + m] = acc[r] + cs[1][row][m] + bias;
        }
    }
}

extern "C" void kernel_launch(void* const* d_in, const int* in_sizes, int n_in,
                              void* d_out, int out_size, void* d_ws, size_t ws_size,
                              hipStream_t stream) {
    const float* z       = (const float*)d_in[0];
    const float* Xi      = (const float*)d_in[1];
    const float* Xi_mask = (const float*)d_in[2];
    // d_in[3]=z_mean, d_in[4]=z_std: unused by the reference
    float* out = (float*)d_out;
    uint4* Bp  = (uint4*)d_ws;   // NCHUNK*64*16 = 565,248 bytes

    sindy_prep<<<NGRAN / 4, 256, 0, stream>>>(Xi, Xi_mask, (uint2*)d_ws, ws_size);
    sindy_mfma<<<NBLK, 256, 0, stream>>>(z, Xi, Xi_mask, Bp, out);
}